// Round 1
// baseline (369.408 us; speedup 1.0000x reference)
//
#include <hip/hip_runtime.h>

// VQ-VAE vector quantizer, MI355X fp32 baseline.
// z: [16, 256, 32, 32] f32, emb_w: [1024, 256] f32
// out: z_q [16,256,32,32] f32 (4194304) ++ loss scalar (1 float)

#define K_CODES 1024
#define D_DIM   256
#define N_VEC   16384   // 16 * 32 * 32
#define HW      1024    // 32*32
#define ZQ_SIZE 4194304

// ---------------- ws layout (floats) ----------------
// emb_t : [256][1024]  offset 0        (262144 floats)
// enorm : [1024]       offset 262144
// idx   : [16384] int  offset 263168

// ---------------- kernel 1: transpose emb -> emb_t[d][k] ----------------
__global__ void vq_transpose(const float* __restrict__ emb, float* __restrict__ emb_t) {
    __shared__ float tile[32][33];
    const int kt = blockIdx.x & 31;   // 32 k-tiles
    const int dt = blockIdx.x >> 5;   // 8 d-tiles
    const int c  = threadIdx.x & 31;
    const int r4 = threadIdx.x >> 5;  // 0..7
    const int k0 = kt * 32, d0 = dt * 32;
#pragma unroll
    for (int p = 0; p < 4; ++p) {
        int r = r4 * 4 + p;
        tile[r][c] = emb[(k0 + r) * D_DIM + d0 + c];
    }
    __syncthreads();
#pragma unroll
    for (int p = 0; p < 4; ++p) {
        int r = r4 * 4 + p;
        emb_t[(d0 + r) * K_CODES + k0 + c] = tile[c][r];
    }
}

// ---------------- kernel 2: enorm[k] = sum_d emb[k][d]^2 ; zero loss ----------------
__global__ void vq_enorm(const float* __restrict__ emb, float* __restrict__ enorm,
                         float* __restrict__ loss_slot) {
    const int k = blockIdx.x;
    const int lane = threadIdx.x;   // block = 64 (one wave)
    float s = 0.f;
#pragma unroll
    for (int p = 0; p < 4; ++p) {
        float v = emb[k * D_DIM + lane + p * 64];
        s += v * v;
    }
#pragma unroll
    for (int off = 32; off >= 1; off >>= 1) s += __shfl_down(s, off);
    if (lane == 0) enorm[k] = s;
    if (k == 0 && lane == 0) *loss_slot = 0.f;
}

// ---------------- kernel 3: fused dot-product + argmin ----------------
// 512 blocks x 256 threads. Block handles 32 consecutive n (one b), all K=1024.
// Thread (ty = wave 0..3, tx = lane 0..63): rows ty*8..ty*8+7, cols tx*16..tx*16+15.
// d staged in chunks of 8 (LDS). B tile XOR-swizzled at float4 granularity.
__launch_bounds__(256)
__global__ void vq_argmin(const float* __restrict__ z, const float* __restrict__ emb_t,
                          const float* __restrict__ enorm, int* __restrict__ idxout) {
    __shared__ float As[8][32];       // 1 KB
    __shared__ float Bs[8 * 1024];    // 32 KB, swizzled float4 granules

    const int tid = threadIdx.x;
    const int tx  = tid & 63;
    const int ty  = tid >> 6;         // wave id 0..3
    const int n0  = blockIdx.x * 32;
    const int b   = n0 >> 10;
    const int hw0 = n0 & 1023;
    const float* zb = z + (size_t)b * (D_DIM * HW) + hw0;

    // precompute swizzled B read offsets (granule = float4)
    int gofs[4];
#pragma unroll
    for (int j = 0; j < 4; ++j) {
        int g = tx * 4 + j;
        gofs[j] = (g ^ ((g >> 3) & 7)) * 4;   // float offset within row
    }

    float4 acc[8][4];
#pragma unroll
    for (int i = 0; i < 8; ++i)
#pragma unroll
        for (int j = 0; j < 4; ++j) acc[i][j] = make_float4(0.f, 0.f, 0.f, 0.f);

    for (int dc = 0; dc < 32; ++dc) {
        const int d0 = dc * 8;
        __syncthreads();
        // A tile: 8 d-rows x 32 n (256 floats, one per thread)
        {
            int dd = tid >> 5, nl = tid & 31;
            As[dd][nl] = zb[(d0 + dd) * HW + nl];
        }
        // B tile: 8 d-rows x 1024 k = 2048 float4 granules, 8 per thread
#pragma unroll
        for (int p = 0; p < 8; ++p) {
            int t2 = p * 256 + tid;
            int dd = t2 >> 8;       // 0..7
            int gw = t2 & 255;      // granule within row
            float4 v = *(const float4*)(emb_t + (size_t)(d0 + dd) * K_CODES + gw * 4);
            int gs = gw ^ ((gw >> 3) & 7);
            *(float4*)(Bs + dd * 1024 + gs * 4) = v;
        }
        __syncthreads();

#pragma unroll
        for (int dd = 0; dd < 8; ++dd) {
            const float4* arow = (const float4*)(&As[dd][ty * 8]);
            float4 a0 = arow[0], a1 = arow[1];
            float a[8] = {a0.x, a0.y, a0.z, a0.w, a1.x, a1.y, a1.z, a1.w};
            const float* brow = Bs + dd * 1024;
            float4 bv[4];
#pragma unroll
            for (int j = 0; j < 4; ++j) bv[j] = *(const float4*)(brow + gofs[j]);
#pragma unroll
            for (int i = 0; i < 8; ++i) {
#pragma unroll
                for (int j = 0; j < 4; ++j) {
                    acc[i][j].x += a[i] * bv[j].x;
                    acc[i][j].y += a[i] * bv[j].y;
                    acc[i][j].z += a[i] * bv[j].z;
                    acc[i][j].w += a[i] * bv[j].w;
                }
            }
        }
    }

    // epilogue: s_k = enorm[k] - 2*dot; per-row argmin, first-index tie-break
    float4 en[4];
#pragma unroll
    for (int j = 0; j < 4; ++j) en[j] = *(const float4*)(enorm + tx * 16 + j * 4);

#pragma unroll
    for (int i = 0; i < 8; ++i) {
        float mv = 1e30f; int mk = 0;
#pragma unroll
        for (int j = 0; j < 4; ++j) {
            const int kb = tx * 16 + j * 4;
            float s;
            s = en[j].x - 2.f * acc[i][j].x; if (s < mv) { mv = s; mk = kb + 0; }
            s = en[j].y - 2.f * acc[i][j].y; if (s < mv) { mv = s; mk = kb + 1; }
            s = en[j].z - 2.f * acc[i][j].z; if (s < mv) { mv = s; mk = kb + 2; }
            s = en[j].w - 2.f * acc[i][j].w; if (s < mv) { mv = s; mk = kb + 3; }
        }
        // full-wave (64-lane) min-reduce with lowest-index tie-break
#pragma unroll
        for (int off = 32; off >= 1; off >>= 1) {
            float ov = __shfl_xor(mv, off);
            int   oi = __shfl_xor(mk, off);
            if (ov < mv || (ov == mv && oi < mk)) { mv = ov; mk = oi; }
        }
        if (tx == 0) idxout[n0 + ty * 8 + i] = mk;
    }
}

// ---------------- kernel 4: gather output + loss ----------------
__global__ void vq_output(const float* __restrict__ z, const float* __restrict__ emb,
                          const int* __restrict__ idx, float* __restrict__ out,
                          float* __restrict__ loss) {
    const int f = blockIdx.x * 256 + threadIdx.x;
    const int hw = f & 1023;
    const int d  = (f >> 10) & 255;
    const int b  = f >> 18;
    const int n  = b * HW + hw;
    const int kk = idx[n];
    const float zq = emb[kk * D_DIM + d];
    const float zv = z[f];
    out[f] = zq;
    float diff = zq - zv;
    float p = diff * diff;
    // wave reduce then cross-wave via LDS
    __shared__ float red[4];
#pragma unroll
    for (int off = 32; off >= 1; off >>= 1) p += __shfl_down(p, off);
    const int lane = threadIdx.x & 63, w = threadIdx.x >> 6;
    if (lane == 0) red[w] = p;
    __syncthreads();
    if (threadIdx.x == 0) {
        float s = red[0] + red[1] + red[2] + red[3];
        atomicAdd(loss, s * (1.25f / (float)ZQ_SIZE));
    }
}

extern "C" void kernel_launch(void* const* d_in, const int* in_sizes, int n_in,
                              void* d_out, int out_size, void* d_ws, size_t ws_size,
                              hipStream_t stream) {
    const float* z   = (const float*)d_in[0];   // 4194304
    const float* emb = (const float*)d_in[1];   // 262144
    float* out  = (float*)d_out;                // 4194304 + 1
    float* loss = out + ZQ_SIZE;

    float* emb_t = (float*)d_ws;                    // 262144 floats
    float* enorm = emb_t + 262144;                  // 1024 floats
    int*   idx   = (int*)(enorm + 1024);            // 16384 ints

    vq_transpose<<<256, 256, 0, stream>>>(emb, emb_t);
    vq_enorm<<<1024, 64, 0, stream>>>(emb, enorm, loss);
    vq_argmin<<<512, 256, 0, stream>>>(z, emb_t, enorm, idx);
    vq_output<<<16384, 256, 0, stream>>>(z, emb, idx, out, loss);
}

// Round 2
// 67.192 us; speedup vs baseline: 5.4978x; 5.4978x over previous
//
#include <hip/hip_runtime.h>

// VQ-VAE vector quantizer, MI355X. bf16-MFMA argmin + atomic-free reductions.
// z: [16, 256, 32, 32] f32, emb_w: [1024, 256] f32
// out: z_q [16,256,32,32] f32 (4194304) ++ loss scalar (1 float)

#define K_CODES 1024
#define D_DIM   256
#define N_VEC   16384
#define HW      1024
#define ZQ_SIZE 4194304

typedef unsigned short ushort_t;
typedef short bf16x8 __attribute__((ext_vector_type(8)));
typedef float f32x16 __attribute__((ext_vector_type(16)));

__device__ __forceinline__ ushort_t f2bf(float x) {
    unsigned int b = __float_as_uint(x);
    b += 0x7fffu + ((b >> 16) & 1u);   // RNE
    return (ushort_t)(b >> 16);
}

__device__ __forceinline__ void gload_lds16(const void* g, void* l) {
    __builtin_amdgcn_global_load_lds(
        (const __attribute__((address_space(1))) void*)g,
        (__attribute__((address_space(3))) void*)l, 16, 0, 0);
}

// ---------- kernel 1: emb f32 -> bf16 + enorm ----------
__global__ void vq_emb_prep(const float* __restrict__ emb, ushort_t* __restrict__ Bbf,
                            float* __restrict__ enorm) {
    const int w = threadIdx.x >> 6, l = threadIdx.x & 63;
    const int k = blockIdx.x * 4 + w;
    const float4 v = *(const float4*)(emb + k * D_DIM + l * 4);
    ushort4 o;
    o.x = f2bf(v.x); o.y = f2bf(v.y); o.z = f2bf(v.z); o.w = f2bf(v.w);
    *(ushort4*)(Bbf + k * D_DIM + l * 4) = o;
    float s = v.x * v.x + v.y * v.y + v.z * v.z + v.w * v.w;
#pragma unroll
    for (int off = 32; off >= 1; off >>= 1) s += __shfl_xor(s, off);
    if (l == 0) enorm[k] = s;
}

// ---------- kernel 2: z [b][d][hw] f32 -> A_bf [b*1024+hw][d] bf16 ----------
__global__ void vq_z_prep(const float* __restrict__ z, ushort_t* __restrict__ Abf) {
    __shared__ float tile[32][33];
    const int bid = blockIdx.x;
    const int ht = bid & 31, dt = (bid >> 5) & 7, b = bid >> 8;
    const int tid = threadIdx.x;
    const int hwo = tid & 31, dr = tid >> 5;
    const float* zp = z + ((size_t)(b * 256 + dt * 32)) * 1024 + ht * 32;
#pragma unroll
    for (int p = 0; p < 4; ++p)
        tile[dr + p * 8][hwo] = zp[(size_t)(dr + p * 8) * 1024 + hwo];
    __syncthreads();
    const int hr = tid >> 3, d4 = (tid & 7) * 4;
    ushort4 o;
    o.x = f2bf(tile[d4 + 0][hr]); o.y = f2bf(tile[d4 + 1][hr]);
    o.z = f2bf(tile[d4 + 2][hr]); o.w = f2bf(tile[d4 + 3][hr]);
    *(ushort4*)(Abf + (size_t)(b * 1024 + ht * 32 + hr) * 256 + dt * 32 + d4) = o;
}

// ---------- kernel 3: MFMA GEMM + partial argmin ----------
// grid = 128 m-tiles x 8 n-panels. block 256 thr (4 waves, 2x2 wave grid).
// block tile 128m x 128n, K=256 in 4 chunks of 64.
__launch_bounds__(256)
__global__ void vq_argmin_mfma(const ushort_t* __restrict__ Abf, const ushort_t* __restrict__ Bbf,
                               const float* __restrict__ enorm,
                               unsigned long long* __restrict__ part) {
    __shared__ ushort_t As[128 * 64];   // 16 KB, 16B-granule XOR-swizzled
    __shared__ ushort_t Bs[128 * 64];   // 16 KB

    const int tid = threadIdx.x;
    const int w = tid >> 6, l = tid & 63;
    const int wm = w >> 1, wn = w & 1;
    const int lane31 = l & 31, hi = l >> 5;
    const int mt = blockIdx.x >> 3, np = blockIdx.x & 7;
    const int m0 = mt * 128, n0 = np * 128;

    f32x16 acc[2][2];
#pragma unroll
    for (int mi = 0; mi < 2; ++mi)
#pragma unroll
        for (int ni = 0; ni < 2; ++ni)
#pragma unroll
            for (int r = 0; r < 16; ++r) acc[mi][ni][r] = 0.f;

    for (int t = 0; t < 4; ++t) {
        __syncthreads();
        // stage A,B chunk [128 rows][64 k] bf16: 1024 granules of 16B each.
        // LDS dest linear; global source pre-permuted so a swizzled READ sees
        // logical (r,c) at phys granule c ^ (r&7)  [both-sides-or-neither rule]
#pragma unroll
        for (int c4 = 0; c4 < 4; ++c4) {
            int g = c4 * 256 + w * 64 + l;
            int r = g >> 3, cp = g & 7, cg = cp ^ (r & 7);
            gload_lds16(Abf + ((size_t)(m0 + r) * 256 + t * 64 + cg * 8),
                        As + (size_t)(c4 * 256 + w * 64) * 8);
            gload_lds16(Bbf + ((size_t)(n0 + r) * 256 + t * 64 + cg * 8),
                        Bs + (size_t)(c4 * 256 + w * 64) * 8);
        }
        __syncthreads();
#pragma unroll
        for (int s = 0; s < 4; ++s) {
            const int cgr = s * 2 + hi;   // logical 16B-granule (8 bf16 of k)
            bf16x8 a[2], bb[2];
#pragma unroll
            for (int mi = 0; mi < 2; ++mi) {
                int r = wm * 64 + mi * 32 + lane31;
                int cp = cgr ^ (r & 7);
                a[mi] = *(const bf16x8*)(As + r * 64 + cp * 8);
            }
#pragma unroll
            for (int ni = 0; ni < 2; ++ni) {
                int r = wn * 64 + ni * 32 + lane31;
                int cp = cgr ^ (r & 7);
                bb[ni] = *(const bf16x8*)(Bs + r * 64 + cp * 8);
            }
#pragma unroll
            for (int mi = 0; mi < 2; ++mi)
#pragma unroll
                for (int ni = 0; ni < 2; ++ni)
                    acc[mi][ni] = __builtin_amdgcn_mfma_f32_32x32x16_bf16(
                        a[mi], bb[ni], acc[mi][ni], 0, 0, 0);
        }
    }

    // epilogue: score = enorm[k] - 2*dot; pack (score,k) sortable u64; reduce.
    const float en[2] = { enorm[n0 + wn * 64 + lane31],
                          enorm[n0 + wn * 64 + 32 + lane31] };
    const unsigned int kg[2] = { (unsigned int)(n0 + wn * 64 + lane31),
                                 (unsigned int)(n0 + wn * 64 + 32 + lane31) };
#pragma unroll
    for (int mi = 0; mi < 2; ++mi) {
#pragma unroll
        for (int reg = 0; reg < 16; ++reg) {
            unsigned long long p = ~0ULL;
#pragma unroll
            for (int ni = 0; ni < 2; ++ni) {
                float sc = en[ni] - 2.0f * acc[mi][ni][reg];
                unsigned int b = __float_as_uint(sc);
                unsigned int u = b ^ (unsigned int)(((int)b >> 31) | 0x80000000);
                unsigned long long pk = ((unsigned long long)u << 32) | kg[ni];
                p = pk < p ? pk : p;
            }
#pragma unroll
            for (int off = 16; off >= 1; off >>= 1) {
                unsigned long long q = __shfl_xor(p, off);
                p = q < p ? q : p;
            }
            if (lane31 == 0) {
                int mg = m0 + wm * 64 + mi * 32 + (reg & 3) + 8 * (reg >> 2) + 4 * hi;
                part[(size_t)mg * 16 + np * 2 + wn] = p;
            }
        }
    }
}

// ---------- kernel 4: reduce 16 partials per row -> idx ----------
__global__ void vq_idx_red(const unsigned long long* __restrict__ part, int* __restrict__ idx) {
    const int m = blockIdx.x * 256 + threadIdx.x;
    const unsigned long long* p = part + (size_t)m * 16;
    unsigned long long best = p[0];
#pragma unroll
    for (int i = 1; i < 16; ++i) { unsigned long long q = p[i]; best = q < best ? q : best; }
    idx[m] = (int)(best & 0xffffffffu);
}

// ---------- kernel 5: gather output + per-block loss partials ----------
__global__ void vq_output(const float* __restrict__ z, const float* __restrict__ emb,
                          const int* __restrict__ idx, float* __restrict__ out,
                          float* __restrict__ partials) {
    const int i = blockIdx.x * 256 + threadIdx.x;
    const int f = i * 4;
    const int b = f >> 18, hw = f & 1023, d = (f >> 10) & 255;
    const int n = b * 1024 + hw;
    const float4 zv = *(const float4*)(z + f);
    const int k0 = idx[n], k1 = idx[n + 1], k2 = idx[n + 2], k3 = idx[n + 3];
    float4 q;
    q.x = emb[k0 * D_DIM + d];
    q.y = emb[k1 * D_DIM + d];
    q.z = emb[k2 * D_DIM + d];
    q.w = emb[k3 * D_DIM + d];
    *(float4*)(out + f) = q;
    float dx = q.x - zv.x, dy = q.y - zv.y, dz = q.z - zv.z, dw = q.w - zv.w;
    float s = dx * dx + dy * dy + dz * dz + dw * dw;
#pragma unroll
    for (int off = 32; off >= 1; off >>= 1) s += __shfl_xor(s, off);
    __shared__ float red[4];
    const int lane = threadIdx.x & 63, wv = threadIdx.x >> 6;
    if (lane == 0) red[wv] = s;
    __syncthreads();
    if (threadIdx.x == 0)
        partials[blockIdx.x] = red[0] + red[1] + red[2] + red[3];
}

// ---------- kernel 6: final loss ----------
__global__ void vq_loss_final(const float* __restrict__ partials, float* __restrict__ loss) {
    const float4 v = *(const float4*)(partials + threadIdx.x * 4);
    float s = v.x + v.y + v.z + v.w;
#pragma unroll
    for (int off = 32; off >= 1; off >>= 1) s += __shfl_xor(s, off);
    __shared__ float red[16];
    const int lane = threadIdx.x & 63, wv = threadIdx.x >> 6;
    if (lane == 0) red[wv] = s;
    __syncthreads();
    if (threadIdx.x == 0) {
        float t = 0.f;
#pragma unroll
        for (int i = 0; i < 16; ++i) t += red[i];
        loss[0] = t * (1.25f / (float)ZQ_SIZE);
    }
}

extern "C" void kernel_launch(void* const* d_in, const int* in_sizes, int n_in,
                              void* d_out, int out_size, void* d_ws, size_t ws_size,
                              hipStream_t stream) {
    const float* z   = (const float*)d_in[0];
    const float* emb = (const float*)d_in[1];
    float* out  = (float*)d_out;
    float* loss = out + ZQ_SIZE;

    char* ws = (char*)d_ws;
    ushort_t* Abf               = (ushort_t*)(ws);                    // 8388608 B
    ushort_t* Bbf               = (ushort_t*)(ws + 8388608);          // 524288 B
    float* enorm                = (float*)(ws + 8912896);             // 4096 B
    unsigned long long* part    = (unsigned long long*)(ws + 8916992);// 2097152 B
    int* idx                    = (int*)(ws + 11014144);              // 65536 B
    float* partials             = (float*)(ws + 11079680);            // 16384 B

    vq_emb_prep<<<256, 256, 0, stream>>>(emb, Bbf, enorm);
    vq_z_prep<<<4096, 256, 0, stream>>>(z, Abf);
    vq_argmin_mfma<<<1024, 256, 0, stream>>>(Abf, Bbf, enorm, part);
    vq_idx_red<<<64, 256, 0, stream>>>(part, idx);
    vq_output<<<4096, 256, 0, stream>>>(z, emb, idx, out, partials);
    vq_loss_final<<<1, 1024, 0, stream>>>(partials, loss);
}

// Round 3
// 56.301 us; speedup vs baseline: 6.5613x; 1.1934x over previous
//
#include <hip/hip_runtime.h>

// VQ-VAE vector quantizer, MI355X. 4 kernels:
//  K1 vq_prep      : z->Abf bf16 [n][d] + znorm ; emb->Bbf bf16 + enorm ; emb->emb_t f32
//  K2 vq_argmin    : bf16 MFMA GEMM + packed (score,idx) partials, dbuf staging, XCD swizzle
//  K3 vq_idx_loss  : 16-way partial min -> idx ; loss = sum(znorm + minscore) per block
//  K4 vq_out_gather: out[b][d][hw] = emb_t[d][idx[n]] ; block 0 finalizes loss
// z: [16,256,32,32] f32, emb_w: [1024,256] f32
// out: z_q f32 (4194304) ++ loss scalar (1 float)

#define K_CODES 1024
#define D_DIM   256
#define N_VEC   16384
#define ZQ_SIZE 4194304

typedef unsigned short ushort_t;
typedef short bf16x8 __attribute__((ext_vector_type(8)));
typedef float f32x16 __attribute__((ext_vector_type(16)));

__device__ __forceinline__ ushort_t f2bf(float x) {
    unsigned int b = __float_as_uint(x);
    b += 0x7fffu + ((b >> 16) & 1u);   // RNE
    return (ushort_t)(b >> 16);
}

__device__ __forceinline__ void gload_lds16(const void* g, void* l) {
    __builtin_amdgcn_global_load_lds(
        (const __attribute__((address_space(1))) void*)g,
        (__attribute__((address_space(3))) void*)l, 16, 0, 0);
}

// ---------------- K1: all prep work, blockIdx-branched ----------------
// bid [0,512)   : z -> Abf bf16 [n][256] + znorm[n]   (block = one (b,ht), dt loop)
// bid [512,768) : emb -> Bbf bf16 + enorm
// bid [768,1024): emb -> emb_t[d][k] f32 transpose
__global__ void vq_prep(const float* __restrict__ z, const float* __restrict__ emb,
                        ushort_t* __restrict__ Abf, float* __restrict__ znorm,
                        ushort_t* __restrict__ Bbf, float* __restrict__ enorm,
                        float* __restrict__ emb_t) {
    __shared__ float tile[32][33];
    const int bid = blockIdx.x;
    const int tid = threadIdx.x;

    if (bid < 512) {
        const int b = bid >> 5, ht = bid & 31;
        const int dr = tid >> 5, hwo = tid & 31;     // load mapping
        const int hr = tid >> 3, d4 = (tid & 7) * 4; // consume mapping
        const float* zb = z + (size_t)b * (256 * 1024) + ht * 32;
        float nacc = 0.f;
        for (int dt = 0; dt < 8; ++dt) {
#pragma unroll
            for (int p = 0; p < 4; ++p)
                tile[dr + p * 8][hwo] = zb[(size_t)(dt * 32 + dr + p * 8) * 1024 + hwo];
            __syncthreads();
            float v0 = tile[d4 + 0][hr], v1 = tile[d4 + 1][hr];
            float v2 = tile[d4 + 2][hr], v3 = tile[d4 + 3][hr];
            nacc += v0 * v0 + v1 * v1 + v2 * v2 + v3 * v3;
            ushort4 o;
            o.x = f2bf(v0); o.y = f2bf(v1); o.z = f2bf(v2); o.w = f2bf(v3);
            *(ushort4*)(Abf + (size_t)(b * 1024 + ht * 32 + hr) * 256 + dt * 32 + d4) = o;
            __syncthreads();
        }
        nacc += __shfl_xor(nacc, 1);
        nacc += __shfl_xor(nacc, 2);
        nacc += __shfl_xor(nacc, 4);
        if ((tid & 7) == 0) znorm[b * 1024 + ht * 32 + hr] = nacc;
    } else if (bid < 768) {
        const int w = tid >> 6, l = tid & 63;
        const int k = (bid - 512) * 4 + w;
        const float4 v = *(const float4*)(emb + k * D_DIM + l * 4);
        ushort4 o;
        o.x = f2bf(v.x); o.y = f2bf(v.y); o.z = f2bf(v.z); o.w = f2bf(v.w);
        *(ushort4*)(Bbf + k * D_DIM + l * 4) = o;
        float s = v.x * v.x + v.y * v.y + v.z * v.z + v.w * v.w;
#pragma unroll
        for (int off = 32; off >= 1; off >>= 1) s += __shfl_xor(s, off);
        if (l == 0) enorm[k] = s;
    } else {
        const int t = bid - 768;
        const int kt = t & 31, dt = t >> 5;
        const int c = tid & 31, r4 = tid >> 5;
        const int k0 = kt * 32, d0 = dt * 32;
#pragma unroll
        for (int p = 0; p < 4; ++p) {
            int r = r4 * 4 + p;
            tile[r][c] = emb[(k0 + r) * D_DIM + d0 + c];
        }
        __syncthreads();
#pragma unroll
        for (int p = 0; p < 4; ++p) {
            int r = r4 * 4 + p;
            emb_t[(d0 + r) * K_CODES + k0 + c] = tile[c][r];
        }
    }
}

// ---------------- K2: MFMA GEMM + partial argmin (dbuf, XCD-swizzled) ----------------
__device__ __forceinline__ void stage_chunk(const ushort_t* __restrict__ Abf,
                                            const ushort_t* __restrict__ Bbf,
                                            ushort_t* AsBuf, ushort_t* BsBuf,
                                            int m0, int n0, int t, int w, int l) {
#pragma unroll
    for (int c4 = 0; c4 < 4; ++c4) {
        int g = c4 * 256 + w * 64 + l;
        int r = g >> 3, cp = g & 7, cg = cp ^ (r & 7);
        gload_lds16(Abf + ((size_t)(m0 + r) * 256 + t * 64 + cg * 8),
                    AsBuf + (size_t)(c4 * 256 + w * 64) * 8);
        gload_lds16(Bbf + ((size_t)(n0 + r) * 256 + t * 64 + cg * 8),
                    BsBuf + (size_t)(c4 * 256 + w * 64) * 8);
    }
}

__launch_bounds__(256)
__global__ void vq_argmin_mfma(const ushort_t* __restrict__ Abf, const ushort_t* __restrict__ Bbf,
                               const float* __restrict__ enorm,
                               unsigned long long* __restrict__ part) {
    __shared__ ushort_t As[2][128 * 64];   // 2 x 16 KB
    __shared__ ushort_t Bs[2][128 * 64];   // 2 x 16 KB

    const int tid = threadIdx.x;
    const int w = tid >> 6, l = tid & 63;
    const int wm = w >> 1, wn = w & 1;
    const int lane31 = l & 31, hi = l >> 5;
    // XCD swizzle: all 8 n-panels of one m-tile land on one XCD's L2
    const int bid = blockIdx.x;
    const int xcd = bid & 7, j = bid >> 3;
    const int mt = xcd * 16 + (j & 15), np = j >> 4;
    const int m0 = mt * 128, n0 = np * 128;

    f32x16 acc[2][2];
#pragma unroll
    for (int mi = 0; mi < 2; ++mi)
#pragma unroll
        for (int ni = 0; ni < 2; ++ni)
#pragma unroll
            for (int r = 0; r < 16; ++r) acc[mi][ni][r] = 0.f;

    stage_chunk(Abf, Bbf, As[0], Bs[0], m0, n0, 0, w, l);
    __syncthreads();

    for (int t = 0; t < 4; ++t) {
        if (t < 3)
            stage_chunk(Abf, Bbf, As[(t + 1) & 1], Bs[(t + 1) & 1], m0, n0, t + 1, w, l);
        const ushort_t* Ab = As[t & 1];
        const ushort_t* Bb = Bs[t & 1];
#pragma unroll
        for (int s = 0; s < 4; ++s) {
            const int cgr = s * 2 + hi;
            bf16x8 a[2], bb[2];
#pragma unroll
            for (int mi = 0; mi < 2; ++mi) {
                int r = wm * 64 + mi * 32 + lane31;
                int cp = cgr ^ (r & 7);
                a[mi] = *(const bf16x8*)(Ab + r * 64 + cp * 8);
            }
#pragma unroll
            for (int ni = 0; ni < 2; ++ni) {
                int r = wn * 64 + ni * 32 + lane31;
                int cp = cgr ^ (r & 7);
                bb[ni] = *(const bf16x8*)(Bb + r * 64 + cp * 8);
            }
#pragma unroll
            for (int mi = 0; mi < 2; ++mi)
#pragma unroll
                for (int ni = 0; ni < 2; ++ni)
                    acc[mi][ni] = __builtin_amdgcn_mfma_f32_32x32x16_bf16(
                        a[mi], bb[ni], acc[mi][ni], 0, 0, 0);
        }
        __syncthreads();   // drains next-chunk loads; protects buffer reuse
    }

    // epilogue: score = enorm[k] - 2*dot; pack (score,k) sortable u64; reduce over cols
    const float en[2] = { enorm[n0 + wn * 64 + lane31],
                          enorm[n0 + wn * 64 + 32 + lane31] };
    const unsigned int kg[2] = { (unsigned int)(n0 + wn * 64 + lane31),
                                 (unsigned int)(n0 + wn * 64 + 32 + lane31) };
#pragma unroll
    for (int mi = 0; mi < 2; ++mi) {
#pragma unroll
        for (int reg = 0; reg < 16; ++reg) {
            unsigned long long p = ~0ULL;
#pragma unroll
            for (int ni = 0; ni < 2; ++ni) {
                float sc = en[ni] - 2.0f * acc[mi][ni][reg];
                unsigned int b = __float_as_uint(sc);
                unsigned int u = b ^ (unsigned int)(((int)b >> 31) | 0x80000000);
                unsigned long long pk = ((unsigned long long)u << 32) | kg[ni];
                p = pk < p ? pk : p;
            }
#pragma unroll
            for (int off = 16; off >= 1; off >>= 1) {
                unsigned long long q = __shfl_xor(p, off);
                p = q < p ? q : p;
            }
            if (lane31 == 0) {
                int mg = m0 + wm * 64 + mi * 32 + (reg & 3) + 8 * (reg >> 2) + 4 * hi;
                part[(size_t)mg * 16 + np * 2 + wn] = p;
            }
        }
    }
}

// ---------------- K3: partial-min -> idx ; loss partial per block ----------------
__global__ void vq_idx_loss(const unsigned long long* __restrict__ part,
                            const float* __restrict__ znorm,
                            int* __restrict__ idx, float* __restrict__ losspart) {
    const int tid = threadIdx.x;
    const int m = blockIdx.x * 256 + tid;
    const unsigned long long* p = part + (size_t)m * 16;
    unsigned long long best = p[0];
#pragma unroll
    for (int i = 1; i < 16; ++i) { unsigned long long q = p[i]; if (q < best) best = q; }
    idx[m] = (int)(best & 0xffffffffu);
    unsigned int u = (unsigned int)(best >> 32);
    unsigned int b = (u & 0x80000000u) ? (u ^ 0x80000000u) : ~u;
    float lsum = znorm[m] + __uint_as_float(b);   // ||z||^2 + ||e||^2 - 2 z.e
#pragma unroll
    for (int off = 32; off >= 1; off >>= 1) lsum += __shfl_xor(lsum, off);
    __shared__ float red[4];
    if ((tid & 63) == 0) red[tid >> 6] = lsum;
    __syncthreads();
    if (tid == 0) losspart[blockIdx.x] = red[0] + red[1] + red[2] + red[3];
}

// ---------------- K4: gather output via emb_t row ; block 0 finalizes loss ----------------
__global__ void vq_out_gather(const float* __restrict__ emb_t, const int* __restrict__ idx,
                              const float* __restrict__ losspart,
                              float* __restrict__ out, float* __restrict__ loss) {
    const int bid = blockIdx.x, tid = threadIdx.x;
    const int d = bid & 255, b = bid >> 8;
    const int hw = tid * 4;
    const int4 kv = *(const int4*)(idx + b * 1024 + hw);
    const float* er = emb_t + (size_t)d * K_CODES;   // one 4 KB row, L1-resident
    float4 q;
    q.x = er[kv.x]; q.y = er[kv.y]; q.z = er[kv.z]; q.w = er[kv.w];
    *(float4*)(out + (size_t)bid * 1024 + hw) = q;
    if (bid == 0 && tid == 0) {
        float s = 0.f;
#pragma unroll
        for (int i = 0; i < 64; ++i) s += losspart[i];
        loss[0] = s * (1.25f / (float)ZQ_SIZE);
    }
}

extern "C" void kernel_launch(void* const* d_in, const int* in_sizes, int n_in,
                              void* d_out, int out_size, void* d_ws, size_t ws_size,
                              hipStream_t stream) {
    const float* z   = (const float*)d_in[0];
    const float* emb = (const float*)d_in[1];
    float* out  = (float*)d_out;
    float* loss = out + ZQ_SIZE;

    char* ws = (char*)d_ws;
    ushort_t* Abf            = (ushort_t*)(ws);                      // 8,388,608 B
    ushort_t* Bbf            = (ushort_t*)(ws + 8388608);            //   524,288 B
    float* emb_t             = (float*)(ws + 8912896);               // 1,048,576 B
    float* enorm             = (float*)(ws + 9961472);               //     4,096 B
    float* znorm             = (float*)(ws + 9965568);               //    65,536 B
    unsigned long long* part = (unsigned long long*)(ws + 10031104); // 2,097,152 B
    int* idx                 = (int*)(ws + 12128256);                //    65,536 B
    float* losspart          = (float*)(ws + 12193792);              //       256 B

    vq_prep<<<1024, 256, 0, stream>>>(z, emb, Abf, znorm, Bbf, enorm, emb_t);
    vq_argmin_mfma<<<1024, 256, 0, stream>>>(Abf, Bbf, enorm, part);
    vq_idx_loss<<<64, 256, 0, stream>>>(part, znorm, idx, losspart);
    vq_out_gather<<<4096, 256, 0, stream>>>(emb_t, idx, losspart, out, loss);
}

// Round 4
// 48.690 us; speedup vs baseline: 7.5870x; 1.1563x over previous
//
#include <hip/hip_runtime.h>

// VQ-VAE vector quantizer, MI355X. 3 kernels:
//  K1 vq_prep   : z->Abf bf16 [n][d] + znorm ; emb->Bbf bf16 + enorm ; emb->emb_t f32 ;
//                 init part = ~0
//  K2 vq_argmin : 256x256x256 bf16 MFMA tile, 1 block/CU, dbuf BK=64 staging;
//                 epilogue packs (score,idx) u64 and atomicMin's per row
//  K3 vq_out    : out[b][d][hw] = emb_t[d][ idx from part[n] ] ; block 0 computes loss
// z: [16,256,32,32] f32, emb_w: [1024,256] f32
// out: z_q f32 (4194304) ++ loss scalar (1 float)

#define K_CODES 1024
#define D_DIM   256
#define N_VEC   16384
#define ZQ_SIZE 4194304

#define BM 256
#define BN 256
#define BK 64

typedef unsigned short ushort_t;
typedef unsigned long long u64;
typedef short bf16x8 __attribute__((ext_vector_type(8)));
typedef float f32x16 __attribute__((ext_vector_type(16)));

__device__ __forceinline__ ushort_t f2bf(float x) {
    unsigned int b = __float_as_uint(x);
    b += 0x7fffu + ((b >> 16) & 1u);   // RNE
    return (ushort_t)(b >> 16);
}

__device__ __forceinline__ void gload_lds16(const void* g, void* l) {
    __builtin_amdgcn_global_load_lds(
        (const __attribute__((address_space(1))) void*)g,
        (__attribute__((address_space(3))) void*)l, 16, 0, 0);
}

// ---------------- K1: all prep work, blockIdx-branched ----------------
// bid [0,512)    : z -> Abf bf16 [n][256] + znorm[n]
// bid [512,768)  : emb -> Bbf bf16 + enorm
// bid [768,1024) : emb -> emb_t[d][k] f32 transpose
// bid [1024,1056): part init to ~0
__global__ void vq_prep(const float* __restrict__ z, const float* __restrict__ emb,
                        ushort_t* __restrict__ Abf, float* __restrict__ znorm,
                        ushort_t* __restrict__ Bbf, float* __restrict__ enorm,
                        float* __restrict__ emb_t, u64* __restrict__ part) {
    __shared__ float tile[32][33];
    const int bid = blockIdx.x;
    const int tid = threadIdx.x;

    if (bid < 512) {
        const int b = bid >> 5, ht = bid & 31;
        const int dr = tid >> 5, hwo = tid & 31;     // load mapping
        const int hr = tid >> 3, d4 = (tid & 7) * 4; // consume mapping
        const float* zb = z + (size_t)b * (256 * 1024) + ht * 32;
        float nacc = 0.f;
        for (int dt = 0; dt < 8; ++dt) {
#pragma unroll
            for (int p = 0; p < 4; ++p)
                tile[dr + p * 8][hwo] = zb[(size_t)(dt * 32 + dr + p * 8) * 1024 + hwo];
            __syncthreads();
            float v0 = tile[d4 + 0][hr], v1 = tile[d4 + 1][hr];
            float v2 = tile[d4 + 2][hr], v3 = tile[d4 + 3][hr];
            nacc += v0 * v0 + v1 * v1 + v2 * v2 + v3 * v3;
            ushort4 o;
            o.x = f2bf(v0); o.y = f2bf(v1); o.z = f2bf(v2); o.w = f2bf(v3);
            *(ushort4*)(Abf + (size_t)(b * 1024 + ht * 32 + hr) * 256 + dt * 32 + d4) = o;
            __syncthreads();
        }
        nacc += __shfl_xor(nacc, 1);
        nacc += __shfl_xor(nacc, 2);
        nacc += __shfl_xor(nacc, 4);
        if ((tid & 7) == 0) znorm[b * 1024 + ht * 32 + hr] = nacc;
    } else if (bid < 768) {
        const int w = tid >> 6, l = tid & 63;
        const int k = (bid - 512) * 4 + w;
        const float4 v = *(const float4*)(emb + k * D_DIM + l * 4);
        ushort4 o;
        o.x = f2bf(v.x); o.y = f2bf(v.y); o.z = f2bf(v.z); o.w = f2bf(v.w);
        *(ushort4*)(Bbf + k * D_DIM + l * 4) = o;
        float s = v.x * v.x + v.y * v.y + v.z * v.z + v.w * v.w;
#pragma unroll
        for (int off = 32; off >= 1; off >>= 1) s += __shfl_xor(s, off);
        if (l == 0) enorm[k] = s;
    } else if (bid < 1024) {
        const int t = bid - 768;
        const int kt = t & 31, dt = t >> 5;
        const int c = tid & 31, r4 = tid >> 5;
        const int k0 = kt * 32, d0 = dt * 32;
#pragma unroll
        for (int p = 0; p < 4; ++p) {
            int r = r4 * 4 + p;
            tile[r][c] = emb[(k0 + r) * D_DIM + d0 + c];
        }
        __syncthreads();
#pragma unroll
        for (int p = 0; p < 4; ++p) {
            int r = r4 * 4 + p;
            emb_t[(d0 + r) * K_CODES + k0 + c] = tile[c][r];
        }
    } else {
        const int i = ((bid - 1024) * 256 + tid) * 2;
        ulonglong2 v; v.x = ~0ull; v.y = ~0ull;
        *(ulonglong2*)(part + i) = v;
    }
}

// ---------------- K2: 256x256 MFMA tile + packed atomicMin argmin ----------------
__launch_bounds__(512, 2)
__global__ void vq_argmin_mfma(const ushort_t* __restrict__ Abf, const ushort_t* __restrict__ Bbf,
                               const float* __restrict__ enorm, u64* __restrict__ part) {
    __shared__ ushort_t As[2][BM * BK];   // 2 x 32 KB
    __shared__ ushort_t Bs[2][BN * BK];   // 2 x 32 KB  (128 KB total)

    const int tid = threadIdx.x;          // 512 threads, 8 waves (2m x 4n)
    const int w = tid >> 6, l = tid & 63;
    const int wm = w >> 2, wn = w & 3;
    const int lane31 = l & 31, hi = l >> 5;
    const int mt = blockIdx.x >> 2, np = blockIdx.x & 3;
    const int m0 = mt * BM, n0 = np * BN;

    f32x16 acc[4][2];
#pragma unroll
    for (int mi = 0; mi < 4; ++mi)
#pragma unroll
        for (int ni = 0; ni < 2; ++ni)
#pragma unroll
            for (int r = 0; r < 16; ++r) acc[mi][ni][r] = 0.f;

    // stage chunk t into buf: 2048 A granules + 2048 B granules of 16B.
    // LDS dest linear (wave-uniform base + lane*16); global src pre-permuted so a
    // swizzled READ sees logical (r,c) at phys granule c ^ (r&7).
    auto stage = [&](int buf, int t) {
#pragma unroll
        for (int c4 = 0; c4 < 4; ++c4) {
            int g = c4 * 512 + tid;
            int r = g >> 3, cp = g & 7, cg = cp ^ (r & 7);
            gload_lds16(Abf + ((size_t)(m0 + r) * 256 + t * 64 + cg * 8),
                        &As[buf][(size_t)g * 8]);
            gload_lds16(Bbf + ((size_t)(n0 + r) * 256 + t * 64 + cg * 8),
                        &Bs[buf][(size_t)g * 8]);
        }
    };

    auto compute = [&](int buf) {
#pragma unroll
        for (int ks = 0; ks < 4; ++ks) {
            const int cgr = ks * 2 + hi;
            bf16x8 a[4], bb[2];
#pragma unroll
            for (int mi = 0; mi < 4; ++mi) {
                int r = wm * 128 + mi * 32 + lane31;
                int cp = cgr ^ (r & 7);
                a[mi] = *(const bf16x8*)(&As[buf][r * 64 + cp * 8]);
            }
#pragma unroll
            for (int ni = 0; ni < 2; ++ni) {
                int r = wn * 64 + ni * 32 + lane31;
                int cp = cgr ^ (r & 7);
                bb[ni] = *(const bf16x8*)(&Bs[buf][r * 64 + cp * 8]);
            }
#pragma unroll
            for (int mi = 0; mi < 4; ++mi)
#pragma unroll
                for (int ni = 0; ni < 2; ++ni)
                    acc[mi][ni] = __builtin_amdgcn_mfma_f32_32x32x16_bf16(
                        a[mi], bb[ni], acc[mi][ni], 0, 0, 0);
        }
    };

    stage(0, 0);
    __syncthreads();                       // chunk 0 resident
    for (int t = 0; t < 4; ++t) {
        if (t < 3) stage((t + 1) & 1, t + 1);   // issue next chunk early
        compute(t & 1);                          // ~2000 cyc/CU hides the staging
        __syncthreads();                         // next chunk drained + buffer-reuse fence
    }

    // epilogue: score = enorm[k] - 2*dot; pack (score,k) sortable u64; min-reduce
    // over this wave's 64 cols, then global atomicMin per row (order-independent).
    float en[2]; unsigned int kg[2];
#pragma unroll
    for (int ni = 0; ni < 2; ++ni) {
        int col = n0 + wn * 64 + ni * 32 + lane31;
        en[ni] = enorm[col];
        kg[ni] = (unsigned int)col;
    }
#pragma unroll
    for (int mi = 0; mi < 4; ++mi) {
#pragma unroll
        for (int reg = 0; reg < 16; ++reg) {
            u64 p = ~0ull;
#pragma unroll
            for (int ni = 0; ni < 2; ++ni) {
                float sc = en[ni] - 2.0f * acc[mi][ni][reg];
                unsigned int b = __float_as_uint(sc);
                unsigned int u = b ^ (unsigned int)(((int)b >> 31) | 0x80000000);
                u64 pk = ((u64)u << 32) | kg[ni];
                if (pk < p) p = pk;
            }
#pragma unroll
            for (int off = 16; off >= 1; off >>= 1) {
                u64 q = __shfl_xor(p, off);
                if (q < p) p = q;
            }
            if (lane31 == 0) {
                int mg = m0 + wm * 128 + mi * 32 + (reg & 3) + 8 * (reg >> 2) + 4 * hi;
                atomicMin(part + mg, p);
            }
        }
    }
}

// ---------------- K3: gather output ; block 0 computes loss ----------------
__global__ void vq_out(const float* __restrict__ emb_t, const u64* __restrict__ part,
                       const float* __restrict__ znorm,
                       float* __restrict__ out, float* __restrict__ loss) {
    const int bid = blockIdx.x, tid = threadIdx.x;
    const int d = bid & 255, b = bid >> 8;
    const int hw = tid * 4;
    const int n = b * 1024 + hw;
    ulonglong2 p01 = *(const ulonglong2*)(part + n);
    ulonglong2 p23 = *(const ulonglong2*)(part + n + 2);
    const float* er = emb_t + (size_t)d * K_CODES;   // one 4 KB row, L1-resident
    float4 q;
    q.x = er[(unsigned int)(p01.x & 0xffffffffu)];
    q.y = er[(unsigned int)(p01.y & 0xffffffffu)];
    q.z = er[(unsigned int)(p23.x & 0xffffffffu)];
    q.w = er[(unsigned int)(p23.y & 0xffffffffu)];
    *(float4*)(out + (size_t)bid * 1024 + hw) = q;

    if (bid == 0) {   // uniform per block: all 256 threads of block 0 participate
        float s = 0.f;
#pragma unroll 16
        for (int i = 0; i < 64; ++i) {
            int m = i * 256 + tid;
            u64 pk = part[m];
            unsigned int u = (unsigned int)(pk >> 32);
            unsigned int fb = (u & 0x80000000u) ? (u ^ 0x80000000u) : ~u;
            s += znorm[m] + __uint_as_float(fb);   // ||z||^2 + ||e||^2 - 2 z.e
        }
#pragma unroll
        for (int off = 32; off >= 1; off >>= 1) s += __shfl_xor(s, off);
        __shared__ float red[4];
        const int lane = tid & 63, wv = tid >> 6;
        if (lane == 0) red[wv] = s;
        __syncthreads();
        if (tid == 0)
            loss[0] = (red[0] + red[1] + red[2] + red[3]) * (1.25f / (float)ZQ_SIZE);
    }
}

extern "C" void kernel_launch(void* const* d_in, const int* in_sizes, int n_in,
                              void* d_out, int out_size, void* d_ws, size_t ws_size,
                              hipStream_t stream) {
    const float* z   = (const float*)d_in[0];
    const float* emb = (const float*)d_in[1];
    float* out  = (float*)d_out;
    float* loss = out + ZQ_SIZE;

    char* ws = (char*)d_ws;
    ushort_t* Abf = (ushort_t*)(ws);              // 8,388,608 B
    ushort_t* Bbf = (ushort_t*)(ws + 8388608);    //   524,288 B
    float* emb_t  = (float*)(ws + 8912896);       // 1,048,576 B
    float* enorm  = (float*)(ws + 9961472);       //     4,096 B
    float* znorm  = (float*)(ws + 9965568);       //    65,536 B
    u64* part     = (u64*)(ws + 10031104);        //   131,072 B

    vq_prep<<<1056, 256, 0, stream>>>(z, emb, Abf, znorm, Bbf, enorm, emb_t, part);
    vq_argmin_mfma<<<256, 512, 0, stream>>>(Abf, Bbf, enorm, part);
    vq_out<<<4096, 256, 0, stream>>>(emb_t, part, znorm, out, loss);
}